// Round 1
// baseline (448.969 us; speedup 1.0000x reference)
//
#include <hip/hip_runtime.h>
#include <stdint.h>

typedef __attribute__((ext_vector_type(8))) short bf16x8;
typedef __attribute__((ext_vector_type(4))) float f32x4;

#define DEVI __device__ __forceinline__

constexpr int B_ = 4, S_ = 2048, D_ = 1024, H_ = 16, DK_ = 64;
constexpr int M_ = B_ * S_;  // 8192 rows total

DEVI short f2bf(float f) {
  union { float f; uint32_t u; } x; x.f = f;
  uint32_t r = x.u + 0x7fffu + ((x.u >> 16) & 1u);  // RNE
  return (short)(uint16_t)(r >> 16);
}

// ---------------- fp32 -> bf16 conversion (memory-bound, vectorized) ----------
__global__ __launch_bounds__(256) void cvt_f32_bf16(const float* __restrict__ in,
                                                    short* __restrict__ out, int n) {
  const int stride = gridDim.x * blockDim.x;
  const int ng = n >> 3;
  for (int g = blockIdx.x * blockDim.x + threadIdx.x; g < ng; g += stride) {
    const f32x4 a = *(const f32x4*)(in + (size_t)g * 8);
    const f32x4 b = *(const f32x4*)(in + (size_t)g * 8 + 4);
    bf16x8 o;
#pragma unroll
    for (int e = 0; e < 4; ++e) { o[e] = f2bf(a[e]); o[e + 4] = f2bf(b[e]); }
    *(bf16x8*)(out + (size_t)g * 8) = o;
  }
}

// ---------------- bf16 GEMM: C[m,n] = sum_k A[m,k]*W[n,k] (+bias)*scale -------
// A row-major [M,K], W row-major [N,K] (torch Linear weight). m97 structure:
// 128x128 tile, BK=32, 4 waves (2x2), 16x16x32 MFMA, global_load_lds width 16.
// MODE 0: bf16 row-major out.  MODE 1: f32 row-major out.
template <int MODE>
__global__ __launch_bounds__(256) void gemm_bt(const short* __restrict__ A,
                                               const short* __restrict__ Bw,
                                               const float* __restrict__ bias,
                                               void* __restrict__ Cout,
                                               int Kdim, int Ndim, float scale) {
  __shared__ short sA[128 * 32];
  __shared__ short sB[128 * 32];
  const int tid = threadIdx.x;
  const int wid = tid >> 6, lane = tid & 63;
  const int m0 = blockIdx.x * 128, n0 = blockIdx.y * 128;
  const int wm = wid >> 1, wn = wid & 1;

  f32x4 acc[4][4];
#pragma unroll
  for (int i = 0; i < 4; ++i)
#pragma unroll
    for (int j = 0; j < 4; ++j) acc[i][j] = (f32x4){0.f, 0.f, 0.f, 0.f};

  // staging: wave w covers tile rows [w*32, w*32+32). Each lane: 16B, 2 issues.
  const int srow = wid * 32 + (lane >> 2);
  const int scol = (lane & 3) * 8;
  const short* gA = A + (size_t)(m0 + srow) * Kdim + scol;
  const short* gB = Bw + (size_t)(n0 + srow) * Kdim + scol;
  short* lA0 = &sA[(wid * 32 + 0) * 32];
  short* lA1 = &sA[(wid * 32 + 16) * 32];
  short* lB0 = &sB[(wid * 32 + 0) * 32];
  short* lB1 = &sB[(wid * 32 + 16) * 32];

  for (int kt = 0; kt < Kdim; kt += 32) {
    __syncthreads();  // previous compute done before overwrite
    __builtin_amdgcn_global_load_lds(
        (const __attribute__((address_space(1))) uint32_t*)(gA + kt),
        (__attribute__((address_space(3))) uint32_t*)lA0, 16, 0, 0);
    __builtin_amdgcn_global_load_lds(
        (const __attribute__((address_space(1))) uint32_t*)(gA + (size_t)16 * Kdim + kt),
        (__attribute__((address_space(3))) uint32_t*)lA1, 16, 0, 0);
    __builtin_amdgcn_global_load_lds(
        (const __attribute__((address_space(1))) uint32_t*)(gB + kt),
        (__attribute__((address_space(3))) uint32_t*)lB0, 16, 0, 0);
    __builtin_amdgcn_global_load_lds(
        (const __attribute__((address_space(1))) uint32_t*)(gB + (size_t)16 * Kdim + kt),
        (__attribute__((address_space(3))) uint32_t*)lB1, 16, 0, 0);
    asm volatile("s_waitcnt vmcnt(0)" ::: "memory");
    __syncthreads();

    bf16x8 af[4], bfr[4];
#pragma unroll
    for (int mf = 0; mf < 4; ++mf)
      af[mf] = *(const bf16x8*)&sA[(wm * 64 + mf * 16 + (lane & 15)) * 32 + ((lane >> 4) * 8)];
#pragma unroll
    for (int nf = 0; nf < 4; ++nf)
      bfr[nf] = *(const bf16x8*)&sB[(wn * 64 + nf * 16 + (lane & 15)) * 32 + ((lane >> 4) * 8)];
#pragma unroll
    for (int mf = 0; mf < 4; ++mf)
#pragma unroll
      for (int nf = 0; nf < 4; ++nf)
        acc[mf][nf] = __builtin_amdgcn_mfma_f32_16x16x32_bf16(af[mf], bfr[nf], acc[mf][nf], 0, 0, 0);
  }

  // epilogue: C/D layout col=lane&15, row=(lane>>4)*4+reg (m89-verified)
#pragma unroll
  for (int mf = 0; mf < 4; ++mf) {
#pragma unroll
    for (int nf = 0; nf < 4; ++nf) {
      const int n = n0 + wn * 64 + nf * 16 + (lane & 15);
      const float bi = bias[n];
#pragma unroll
      for (int r = 0; r < 4; ++r) {
        const int m = m0 + wm * 64 + mf * 16 + ((lane >> 4) * 4) + r;
        const float vv = (acc[mf][nf][r] + bi) * scale;
        if (MODE == 0)
          ((short*)Cout)[(size_t)m * Ndim + n] = f2bf(vv);
        else
          ((float*)Cout)[(size_t)m * Ndim + n] = vv;
      }
    }
  }
}

// ---------------- causal flash attention -------------------------------------
// Q/K/V in bf16 [B,S,D] layout (head h occupies cols h*64..h*64+63).
// Block: 64 q-rows, 4 waves x 16 rows. K-tiles of 64 keys, online softmax fp32.
__global__ __launch_bounds__(256) void attn_fwd(const short* __restrict__ Qf,
                                                const short* __restrict__ Kf,
                                                const short* __restrict__ Vf,
                                                short* __restrict__ AO) {
  __shared__ short sK[64 * 64];      // linear (global_load_lds dest)
  __shared__ short sVT[64 * 72];     // V transposed, padded: 144B rows -> 2-way
  __shared__ float sP[4][16 * 68];   // per-wave P tile, 272B rows (16B aligned)

  const int tid = threadIdx.x, wid = tid >> 6, lane = tid & 63;
  const int bh = blockIdx.y, b = bh >> 4, h = bh & 15;
  const int q0 = blockIdx.x * 64;
  const int qw = q0 + wid * 16;
  const size_t rowbase = (size_t)b * S_ * D_ + (size_t)h * DK_;

  // Q fragments held in registers for the whole kernel (A-operand, scaled at proj)
  bf16x8 aQ[2];
  {
    const int qrow = qw + (lane & 15);
    const short* qp = Qf + rowbase + (size_t)qrow * D_ + ((lane >> 4) * 8);
    aQ[0] = *(const bf16x8*)qp;
    aQ[1] = *(const bf16x8*)(qp + 32);
  }

  float m_run[4], lsum[4];
  f32x4 o[4];
#pragma unroll
  for (int r = 0; r < 4; ++r) { m_run[r] = -1e30f; lsum[r] = 0.f; }
#pragma unroll
  for (int nf = 0; nf < 4; ++nf) o[nf] = (f32x4){0.f, 0.f, 0.f, 0.f};

  const int ks_row = wid * 16 + (lane >> 3);  // K stage row (+ j*8)
  const int ks_col = (lane & 7) * 8;
  const int vt_row = tid >> 2;                // V row 0..63
  const int vt_c0 = (tid & 3) * 16;

  const int ntiles = blockIdx.x + 1;  // causal: keys up to q0+63
  for (int t = 0; t < ntiles; ++t) {
    const int kt = t * 64;
    __syncthreads();
    // stage K tile [64][64] linear via global_load_lds (16B/lane, 2 issues/wave)
    const short* gK = Kf + rowbase + (size_t)(kt + ks_row) * D_ + ks_col;
    __builtin_amdgcn_global_load_lds(
        (const __attribute__((address_space(1))) uint32_t*)gK,
        (__attribute__((address_space(3))) uint32_t*)&sK[(wid * 16) * 64], 16, 0, 0);
    __builtin_amdgcn_global_load_lds(
        (const __attribute__((address_space(1))) uint32_t*)(gK + (size_t)8 * D_),
        (__attribute__((address_space(3))) uint32_t*)&sK[(wid * 16 + 8) * 64], 16, 0, 0);
    // stage V^T [d][k] (manual transpose, padded rows)
    {
      const short* gV = Vf + rowbase + (size_t)(kt + vt_row) * D_ + vt_c0;
      bf16x8 v0 = *(const bf16x8*)gV;
      bf16x8 v1 = *(const bf16x8*)(gV + 8);
#pragma unroll
      for (int e = 0; e < 8; ++e) {
        sVT[(vt_c0 + e) * 72 + vt_row] = v0[e];
        sVT[(vt_c0 + 8 + e) * 72 + vt_row] = v1[e];
      }
    }
    asm volatile("s_waitcnt vmcnt(0)" ::: "memory");
    __syncthreads();

    // ---- QK^T : P[16 q][64 keys] ----
    f32x4 p[4];
#pragma unroll
    for (int nf = 0; nf < 4; ++nf) p[nf] = (f32x4){0.f, 0.f, 0.f, 0.f};
#pragma unroll
    for (int nf = 0; nf < 4; ++nf) {
#pragma unroll
      for (int ks = 0; ks < 2; ++ks) {
        bf16x8 bK = *(const bf16x8*)&sK[(nf * 16 + (lane & 15)) * 64 + ks * 32 + ((lane >> 4) * 8)];
        p[nf] = __builtin_amdgcn_mfma_f32_16x16x32_bf16(aQ[ks], bK, p[nf], 0, 0, 0);
      }
    }
    // causal mask (only diagonal-overlapping tiles need it)
    if (kt + 63 > qw) {
#pragma unroll
      for (int nf = 0; nf < 4; ++nf) {
        const int col = kt + nf * 16 + (lane & 15);
#pragma unroll
        for (int r = 0; r < 4; ++r) {
          const int row = qw + ((lane >> 4) * 4) + r;
          if (col > row) p[nf][r] = -1e30f;
        }
      }
    }
    // ---- online softmax (fp32; row = 16 lanes sharing lane>>4, x 4 regs) ----
    float* pw = &sP[wid][0];
#pragma unroll
    for (int r = 0; r < 4; ++r) {
      float mx = fmaxf(fmaxf(p[0][r], p[1][r]), fmaxf(p[2][r], p[3][r]));
      mx = fmaxf(mx, __shfl_xor(mx, 1));
      mx = fmaxf(mx, __shfl_xor(mx, 2));
      mx = fmaxf(mx, __shfl_xor(mx, 4));
      mx = fmaxf(mx, __shfl_xor(mx, 8));
      const float mnew = fmaxf(m_run[r], mx);
      const float corr = __expf(m_run[r] - mnew);
      float rs = 0.f;
#pragma unroll
      for (int nf = 0; nf < 4; ++nf) {
        const float pe = (p[nf][r] < -1e29f) ? 0.f : __expf(p[nf][r] - mnew);
        p[nf][r] = pe;
        rs += pe;
      }
      rs += __shfl_xor(rs, 1);
      rs += __shfl_xor(rs, 2);
      rs += __shfl_xor(rs, 4);
      rs += __shfl_xor(rs, 8);
      lsum[r] = lsum[r] * corr + rs;
      m_run[r] = mnew;
#pragma unroll
      for (int nf = 0; nf < 4; ++nf) o[nf][r] *= corr;
    }
    // ---- P -> LDS (re-layout D->A operand), then PV ----
#pragma unroll
    for (int nf = 0; nf < 4; ++nf)
#pragma unroll
      for (int r = 0; r < 4; ++r)
        pw[(((lane >> 4) * 4) + r) * 68 + nf * 16 + (lane & 15)] = p[nf][r];
    asm volatile("s_waitcnt lgkmcnt(0)" ::: "memory");
#pragma unroll
    for (int ks = 0; ks < 2; ++ks) {
      const float* pr = &pw[(lane & 15) * 68 + ks * 32 + ((lane >> 4) * 8)];
      f32x4 pa0 = *(const f32x4*)pr;
      f32x4 pa1 = *(const f32x4*)(pr + 4);
      bf16x8 aP;
#pragma unroll
      for (int e = 0; e < 4; ++e) { aP[e] = f2bf(pa0[e]); aP[e + 4] = f2bf(pa1[e]); }
#pragma unroll
      for (int nf = 0; nf < 4; ++nf) {
        bf16x8 bV = *(const bf16x8*)&sVT[(nf * 16 + (lane & 15)) * 72 + ks * 32 + ((lane >> 4) * 8)];
        o[nf] = __builtin_amdgcn_mfma_f32_16x16x32_bf16(aP, bV, o[nf], 0, 0, 0);
      }
    }
  }

  // finalize: normalize and store bf16 [B,S,D]
  float inv[4];
#pragma unroll
  for (int r = 0; r < 4; ++r) inv[r] = 1.f / lsum[r];
#pragma unroll
  for (int nf = 0; nf < 4; ++nf) {
#pragma unroll
    for (int r = 0; r < 4; ++r) {
      const int row = qw + ((lane >> 4) * 4) + r;
      AO[rowbase + (size_t)row * D_ + nf * 16 + (lane & 15)] = f2bf(o[nf][r] * inv[r]);
    }
  }
}

// ---------------- launch ------------------------------------------------------
extern "C" void kernel_launch(void* const* d_in, const int* in_sizes, int n_in,
                              void* d_out, int out_size, void* d_ws, size_t ws_size,
                              hipStream_t stream) {
  (void)in_sizes; (void)n_in; (void)out_size; (void)ws_size;
  const float* q  = (const float*)d_in[0];
  const float* k  = (const float*)d_in[1];
  const float* v  = (const float*)d_in[2];
  // d_in[3] = mask (causal tril) — implemented analytically
  const float* Wq = (const float*)d_in[4];
  const float* bq = (const float*)d_in[5];
  const float* Wk = (const float*)d_in[6];
  const float* bk = (const float*)d_in[7];
  const float* Wv = (const float*)d_in[8];
  const float* bv = (const float*)d_in[9];
  const float* Wo = (const float*)d_in[10];
  const float* bo = (const float*)d_in[11];

  char* ws = (char*)d_ws;
  const size_t MB = 1ull << 20;
  short* wqb = (short*)(ws + 0 * MB);   // 2MB each
  short* wkb = (short*)(ws + 2 * MB);
  short* wvb = (short*)(ws + 4 * MB);
  short* wob = (short*)(ws + 6 * MB);
  short* Qf  = (short*)(ws + 8 * MB);   // 16MB each, bf16 [B,S,D]
  short* Kf  = (short*)(ws + 24 * MB);
  short* Vf  = (short*)(ws + 40 * MB);
  short* xq  = (short*)(ws + 56 * MB);  // bf16 inputs
  short* xk  = (short*)(ws + 72 * MB);
  short* xv  = (short*)(ws + 88 * MB);
  short* AO  = xq;  // xq dead after Q projection; reuse for attention output

  const int BSD = B_ * S_ * D_;
  cvt_f32_bf16<<<4096, 256, 0, stream>>>(q, xq, BSD);
  cvt_f32_bf16<<<4096, 256, 0, stream>>>(k, xk, BSD);
  cvt_f32_bf16<<<4096, 256, 0, stream>>>(v, xv, BSD);
  cvt_f32_bf16<<<512, 256, 0, stream>>>(Wq, wqb, D_ * D_);
  cvt_f32_bf16<<<512, 256, 0, stream>>>(Wk, wkb, D_ * D_);
  cvt_f32_bf16<<<512, 256, 0, stream>>>(Wv, wvb, D_ * D_);
  cvt_f32_bf16<<<512, 256, 0, stream>>>(Wo, wob, D_ * D_);

  dim3 gg(M_ / 128, D_ / 128);
  // Q projection folds the 1/sqrt(DK) score scale
  gemm_bt<0><<<gg, 256, 0, stream>>>(xq, wqb, bq, Qf, D_, D_, 0.125f);
  gemm_bt<0><<<gg, 256, 0, stream>>>(xk, wkb, bk, Kf, D_, D_, 1.0f);
  gemm_bt<0><<<gg, 256, 0, stream>>>(xv, wvb, bv, Vf, D_, D_, 1.0f);

  attn_fwd<<<dim3(S_ / 64, B_ * H_), 256, 0, stream>>>(Qf, Kf, Vf, AO);

  gemm_bt<1><<<gg, 256, 0, stream>>>(AO, wob, bo, d_out, D_, D_, 1.0f);
}